// Round 11
// baseline (139.834 us; speedup 1.0000x reference)
//
#include <hip/hip_runtime.h>

#define N_NODES 50000
#define IN_CH   256
#define HID_CH  64
#define N_EDGES 800000

#define AG_ROWS 64           // nodes per bucket
#define NBUCKET 782          // ceil(50000 / 64)
#define CAPB    1536         // fixed capacity per bucket region (~16 sigma)
#define PTILE   4096         // edges per partition tile
#define NPT     196          // ceil(800000 / 4096)
#define GEMM_BLOCKS 391      // ceil(50000 / 128) at 128 rows per 512-thr block
#define CAP     2048         // aggregate staging capacity (> CAPB)

typedef __attribute__((ext_vector_type(8))) short short8;
typedef __attribute__((ext_vector_type(8))) unsigned short ushort8v;
typedef __attribute__((ext_vector_type(4))) float f32x4;

static __device__ __forceinline__ unsigned short f2bf(float f) {
    unsigned int u = __float_as_uint(f);
    u += 0x7FFF + ((u >> 16) & 1);   // RNE
    return (unsigned short)(u >> 16);
}
static __device__ __forceinline__ float bf2f(unsigned short h) {
    return __uint_as_float(((unsigned int)h) << 16);
}

// ---------------------------------------------------------------------------
// Kernel 0: precompute W B-fragments (bf16) + zero bucket counters.
// ---------------------------------------------------------------------------
__global__ __launch_bounds__(256) void wfrag_kernel(const float* __restrict__ W,
                                                    unsigned short* __restrict__ wfrag,
                                                    int* __restrict__ cnt) {
    const int idx = blockIdx.x * 256 + threadIdx.x;
    if (idx < NBUCKET) cnt[idx] = 0;
    if (idx >= 2048) return;
    const int ks = idx >> 8;
    const int nt = (idx >> 6) & 3;
    const int l  = idx & 63;
    const int q = l >> 4, m = l & 15;
    const int n = nt * 16 + m;
    const int k0 = ks * 32 + q * 8;
    short8 v;
    #pragma unroll
    for (int j = 0; j < 8; ++j) v[j] = (short)f2bf(W[(k0 + j) * HID_CH + n]);
    ((short8*)wfrag)[idx] = v;
}

// ---------------------------------------------------------------------------
// Kernel 1 (fused): blocks [0, GEMM_BLOCKS) -> MFMA GEMM (xwb = bf16(x@W));
// blocks [GEMM_BLOCKS, GEMM_BLOCKS+NPT) -> edge partition into fixed-capacity
// bucket regions. 512 threads per block.
// ---------------------------------------------------------------------------
__global__ __launch_bounds__(512) void gemm_part_kernel(const float* __restrict__ x,
                                                        const unsigned short* __restrict__ wfrag,
                                                        unsigned short* __restrict__ xwb,
                                                        const int* __restrict__ ei,
                                                        int* __restrict__ cnt,
                                                        unsigned int* __restrict__ packed_out) {
    __shared__ int hcnt[NBUCKET];
    __shared__ int excl[NBUCKET];
    __shared__ int lcur[NBUCKET];
    __shared__ int gbase[NBUCKET];
    __shared__ int wsum[8];
    __shared__ unsigned int staged[PTILE];
    __shared__ unsigned short sbkt[PTILE];

    const int t = threadIdx.x;

    if (blockIdx.x < GEMM_BLOCKS) {
        // ---------------- GEMM path: 8 waves, each owns a 16x64 tile --------
        const int wv = t >> 6, lane = t & 63;
        const int q = lane >> 4, m = lane & 15;
        const int row0 = blockIdx.x * 128 + wv * 16;
        const int arow = row0 + m;
        const int arl = arow < N_NODES ? arow : N_NODES - 1;
        const float* xr = x + (size_t)arl * IN_CH + q * 8;
        const short8* wf = (const short8*)wfrag;

        f32x4 acc0 = {0.f,0.f,0.f,0.f}, acc1 = acc0, acc2 = acc0, acc3 = acc0;

        #pragma unroll
        for (int ks = 0; ks < 8; ++ks) {
            const float4 a0 = *(const float4*)(xr + ks * 32);
            const float4 a1 = *(const float4*)(xr + ks * 32 + 4);
            short8 af;
            af[0] = (short)f2bf(a0.x); af[1] = (short)f2bf(a0.y);
            af[2] = (short)f2bf(a0.z); af[3] = (short)f2bf(a0.w);
            af[4] = (short)f2bf(a1.x); af[5] = (short)f2bf(a1.y);
            af[6] = (short)f2bf(a1.z); af[7] = (short)f2bf(a1.w);
            const short8 b0 = wf[(ks * 4 + 0) * 64 + lane];
            const short8 b1 = wf[(ks * 4 + 1) * 64 + lane];
            const short8 b2 = wf[(ks * 4 + 2) * 64 + lane];
            const short8 b3 = wf[(ks * 4 + 3) * 64 + lane];
            acc0 = __builtin_amdgcn_mfma_f32_16x16x32_bf16(af, b0, acc0, 0, 0, 0);
            acc1 = __builtin_amdgcn_mfma_f32_16x16x32_bf16(af, b1, acc1, 0, 0, 0);
            acc2 = __builtin_amdgcn_mfma_f32_16x16x32_bf16(af, b2, acc2, 0, 0, 0);
            acc3 = __builtin_amdgcn_mfma_f32_16x16x32_bf16(af, b3, acc3, 0, 0, 0);
        }

        #pragma unroll
        for (int r = 0; r < 4; ++r) {
            const int row = row0 + q * 4 + r;
            if (row < N_NODES) {
                unsigned short* o = xwb + (size_t)row * HID_CH + m;
                o[0]  = f2bf(acc0[r]);
                o[16] = f2bf(acc1[r]);
                o[32] = f2bf(acc2[r]);
                o[48] = f2bf(acc3[r]);
            }
        }
        return;
    }

    // ---------------- partition path: tile of 4096 edges --------------------
    const int tile0 = (blockIdx.x - GEMM_BLOCKS) * PTILE;
    const int tcnt = min(PTILE, N_EDGES - tile0);

    for (int i = t; i < NBUCKET; i += 512) hcnt[i] = 0;
    __syncthreads();

    int es[8], ed[8];
    #pragma unroll
    for (int i = 0; i < 8; ++i) {
        const int e = tile0 + t + i * 512;
        if (e < N_EDGES) {
            es[i] = ei[e];
            ed[i] = ei[N_EDGES + e];
            atomicAdd(&hcnt[ed[i] >> 6], 1);
        } else es[i] = -1;
    }
    __syncthreads();

    // exclusive scan of 782 counts: pair-per-thread + shfl wave-scan
    const int b0 = 2 * t, b1 = 2 * t + 1;
    const int c0 = (b0 < NBUCKET) ? hcnt[b0] : 0;
    const int c1 = (b1 < NBUCKET) ? hcnt[b1] : 0;
    const int v = c0 + c1;
    int s = v;
    #pragma unroll
    for (int off = 1; off < 64; off <<= 1) {
        const int u = __shfl_up(s, off, 64);
        if ((t & 63) >= off) s += u;
    }
    if ((t & 63) == 63) wsum[t >> 6] = s;
    __syncthreads();
    if (t < 8) {
        const int ws = wsum[t];
        int si = ws;
        #pragma unroll
        for (int off = 1; off < 8; off <<= 1) {
            const int u = __shfl_up(si, off, 64);
            if (t >= off) si += u;
        }
        wsum[t] = si - ws;   // exclusive base for wave t
    }
    __syncthreads();
    const int ex = s - v + wsum[t >> 6];
    if (b0 < NBUCKET) {
        excl[b0] = ex; lcur[b0] = ex;
        if (c0 > 0) gbase[b0] = b0 * CAPB + atomicAdd(&cnt[b0], c0);
    }
    if (b1 < NBUCKET) {
        excl[b1] = ex + c0; lcur[b1] = ex + c0;
        if (c1 > 0) gbase[b1] = b1 * CAPB + atomicAdd(&cnt[b1], c1);
    }
    __syncthreads();

    #pragma unroll
    for (int i = 0; i < 8; ++i) {
        if (es[i] >= 0) {
            const int b = ed[i] >> 6;
            const int pos = atomicAdd(&lcur[b], 1);
            staged[pos] = ((unsigned int)(ed[i] & 63) << 16) | (unsigned int)es[i];
            sbkt[pos] = (unsigned short)b;
        }
    }
    __syncthreads();

    #pragma unroll
    for (int i = 0; i < 8; ++i) {
        const int idx = t + i * 512;
        if (idx < tcnt) {
            const int b = sbkt[idx];
            packed_out[gbase[b] + (idx - excl[b])] = staged[idx];
        }
    }
}

// ---------------------------------------------------------------------------
// Kernel 2: per-bucket aggregate (64 nodes). In-LDS counting sort (wave-0
// shfl scan), then slot-gather: lane = slot*8 + g; slot in [0,8) strides
// edges, g in [0,8) covers channel octet -> ushort8 (16 B/lane) gathers =
// 8 edge-rows / 1 KB per wave instruction. Wave w owns nodes {w*8..w*8+7}
// exclusively -> plain LDS read-add-write. Fused bias + PReLU.
// ---------------------------------------------------------------------------
__global__ __launch_bounds__(512) void aggregate_kernel(const unsigned short* __restrict__ xwb,
                                                        const unsigned int* __restrict__ packed,
                                                        const int* __restrict__ cnt,
                                                        const float* __restrict__ bias,
                                                        const float* __restrict__ prelu_a,
                                                        float* __restrict__ out) {
    __shared__ unsigned int   sp[CAP];        //  8 KB
    __shared__ unsigned short ssrc[CAP];      //  4 KB
    __shared__ int hcnt[AG_ROWS];
    __shared__ int hexcl[AG_ROWS];
    __shared__ int hcur[AG_ROWS];
    __shared__ float acc[AG_ROWS * HID_CH];   // 16 KB

    const int b = blockIdx.x;
    const int t = threadIdx.x;
    const int beg = b * CAPB;
    const int total = min(cnt[b], CAP);
    const int wv = t >> 6, lane = t & 63;
    const int slot = lane >> 3;          // 0..7: edge stride slot
    const int c0 = (lane & 7) * 8;       // channel octet

    #pragma unroll
    for (int i = 0; i < 8; ++i) acc[t + i * 512] = 0.f;
    if (t < AG_ROWS) hcnt[t] = 0;
    __syncthreads();

    // stage + histogram
    for (int i = t; i < total; i += 512) {
        const unsigned int p = packed[beg + i];
        sp[i] = p;
        atomicAdd(&hcnt[p >> 16], 1);
    }
    __syncthreads();

    // exclusive scan of 64 counts by wave 0 (shfl)
    if (t < AG_ROWS) {
        const int v = hcnt[t];
        int s = v;
        #pragma unroll
        for (int off = 1; off < 64; off <<= 1) {
            const int u = __shfl_up(s, off, 64);
            if (t >= off) s += u;
        }
        hexcl[t] = s - v;
        hcur[t]  = s - v;
    }
    __syncthreads();

    // reorder into node-sorted runs
    for (int i = t; i < total; i += 512) {
        const unsigned int p = sp[i];
        const int pos = atomicAdd(&hcur[p >> 16], 1);
        ssrc[pos] = (unsigned short)(p & 0xFFFFu);
    }
    __syncthreads();

    // slot-gather: wave wv owns nodes wv*8 .. wv*8+7
    #pragma unroll
    for (int k = 0; k < 8; ++k) {
        const int nl = wv * 8 + k;
        const int rb = hexcl[nl];
        const int re = rb + hcnt[nl];
        float a[8] = {0.f,0.f,0.f,0.f,0.f,0.f,0.f,0.f};
        int i = rb + slot;
        for (; i + 24 < re; i += 32) {   // 4 loads in flight
            const int s0 = ssrc[i];
            const int s1 = ssrc[i + 8];
            const int s2 = ssrc[i + 16];
            const int s3 = ssrc[i + 24];
            const ushort8v v0 = *(const ushort8v*)(xwb + (size_t)s0 * HID_CH + c0);
            const ushort8v v1 = *(const ushort8v*)(xwb + (size_t)s1 * HID_CH + c0);
            const ushort8v v2 = *(const ushort8v*)(xwb + (size_t)s2 * HID_CH + c0);
            const ushort8v v3 = *(const ushort8v*)(xwb + (size_t)s3 * HID_CH + c0);
            #pragma unroll
            for (int j = 0; j < 8; ++j)
                a[j] += bf2f(v0[j]) + bf2f(v1[j]) + bf2f(v2[j]) + bf2f(v3[j]);
        }
        for (; i < re; i += 8) {
            const int s = ssrc[i];
            const ushort8v v = *(const ushort8v*)(xwb + (size_t)s * HID_CH + c0);
            #pragma unroll
            for (int j = 0; j < 8; ++j) a[j] += bf2f(v[j]);
        }
        // reduce across the 8 slots (lane bits 3,4,5)
        #pragma unroll
        for (int j = 0; j < 8; ++j) {
            a[j] += __shfl_xor(a[j], 8, 64);
            a[j] += __shfl_xor(a[j], 16, 64);
            a[j] += __shfl_xor(a[j], 32, 64);
        }
        if (slot == 0) {   // lanes 0..7 cover the 8 channel octets
            float4* ap = (float4*)&acc[nl * HID_CH + c0];
            float4 lo = ap[0], hi = ap[1];
            lo.x += a[0]; lo.y += a[1]; lo.z += a[2]; lo.w += a[3];
            hi.x += a[4]; hi.y += a[5]; hi.z += a[6]; hi.w += a[7];
            ap[0] = lo; ap[1] = hi;
        }
    }
    __syncthreads();

    // epilogue: bias + PReLU, coalesced float4 writes
    const int node0 = b * AG_ROWS;
    const int nrows = min(AG_ROWS, N_NODES - node0);
    for (int i = t; i < nrows * (HID_CH / 4); i += 512) {
        const int r = i >> 4;
        const int cc = (i & 15) * 4;
        const float4 a4 = *(float4*)&acc[r * HID_CH + cc];
        const float4 bb = *(const float4*)(bias + cc);
        const float4 aa = *(const float4*)(prelu_a + cc);
        float4 rr;
        rr.x = a4.x + bb.x; rr.x = rr.x > 0.f ? rr.x : aa.x * rr.x;
        rr.y = a4.y + bb.y; rr.y = rr.y > 0.f ? rr.y : aa.y * rr.y;
        rr.z = a4.z + bb.z; rr.z = rr.z > 0.f ? rr.z : aa.z * rr.z;
        rr.w = a4.w + bb.w; rr.w = rr.w > 0.f ? rr.w : aa.w * rr.w;
        *(float4*)(out + (size_t)(node0 + r) * HID_CH + cc) = rr;
    }
}

extern "C" void kernel_launch(void* const* d_in, const int* in_sizes, int n_in,
                              void* d_out, int out_size, void* d_ws, size_t ws_size,
                              hipStream_t stream) {
    const float* x       = (const float*)d_in[0];
    const int*   ei      = (const int*)d_in[1];   // [2, E]: src row then dst row
    const float* W       = (const float*)d_in[2];
    const float* bias    = (const float*)d_in[3];
    const float* prelu_a = (const float*)d_in[4];
    float* out = (float*)d_out;

    // workspace layout (16B-aligned)
    char* w = (char*)d_ws;
    unsigned short* xwb    = (unsigned short*)(w);             // 6,400,000 B
    int*            cnt    = (int*)(w + 6400000);              //     3,128 B
    unsigned int*   packed = (unsigned int*)(w + 6403200);     // 4,804,608 B (782*1536*4)
    unsigned short* wfrag  = (unsigned short*)(w + 11207808);  //    32,768 B

    // 0) W -> bf16 B-fragments; zero bucket counters
    wfrag_kernel<<<8, 256, 0, stream>>>(W, wfrag, cnt);

    // 1) fused: gemm (blocks 0..390) + edge partition (blocks 391..586)
    gemm_part_kernel<<<GEMM_BLOCKS + NPT, 512, 0, stream>>>(x, wfrag, xwb, ei, cnt, packed);

    // 2) per-bucket sort + aggregate + bias + PReLU
    aggregate_kernel<<<NBUCKET, 512, 0, stream>>>(xwb, packed, cnt, bias, prelu_a, out);
}

// Round 12
// 129.935 us; speedup vs baseline: 1.0762x; 1.0762x over previous
//
#include <hip/hip_runtime.h>

#define N_NODES 50000
#define IN_CH   256
#define HID_CH  64
#define N_EDGES 800000

#define AG_ROWS 64           // nodes per bucket
#define NBUCKET 782          // ceil(50000 / 64)
#define CAPB    1536         // fixed capacity per bucket region (~16 sigma)
#define PTILE   4096         // edges per partition tile
#define NPT     196          // ceil(800000 / 4096)
#define GEMM_BLOCKS 391      // ceil(50000 / 128) at 128 rows per 512-thr block
#define CAP     2048         // aggregate staging capacity (> CAPB)

typedef __attribute__((ext_vector_type(8))) short short8;
typedef __attribute__((ext_vector_type(4))) float f32x4;

static __device__ __forceinline__ unsigned short f2bf(float f) {
    unsigned int u = __float_as_uint(f);
    u += 0x7FFF + ((u >> 16) & 1);   // RNE
    return (unsigned short)(u >> 16);
}
static __device__ __forceinline__ float bf2f(unsigned short h) {
    return __uint_as_float(((unsigned int)h) << 16);
}

// ---------------------------------------------------------------------------
// Kernel 0: precompute W B-fragments (bf16) + zero bucket counters.
// ---------------------------------------------------------------------------
__global__ __launch_bounds__(256) void wfrag_kernel(const float* __restrict__ W,
                                                    unsigned short* __restrict__ wfrag,
                                                    int* __restrict__ cnt) {
    const int idx = blockIdx.x * 256 + threadIdx.x;
    if (idx < NBUCKET) cnt[idx] = 0;
    if (idx >= 2048) return;
    const int ks = idx >> 8;
    const int nt = (idx >> 6) & 3;
    const int l  = idx & 63;
    const int q = l >> 4, m = l & 15;
    const int n = nt * 16 + m;
    const int k0 = ks * 32 + q * 8;
    short8 v;
    #pragma unroll
    for (int j = 0; j < 8; ++j) v[j] = (short)f2bf(W[(k0 + j) * HID_CH + n]);
    ((short8*)wfrag)[idx] = v;
}

// ---------------------------------------------------------------------------
// Kernel 1 (fused): blocks [0, GEMM_BLOCKS) -> MFMA GEMM (xwb = bf16(x@W));
// blocks [GEMM_BLOCKS, GEMM_BLOCKS+NPT) -> edge partition into fixed-capacity
// bucket regions. 512 threads per block.
// ---------------------------------------------------------------------------
__global__ __launch_bounds__(512) void gemm_part_kernel(const float* __restrict__ x,
                                                        const unsigned short* __restrict__ wfrag,
                                                        unsigned short* __restrict__ xwb,
                                                        const int* __restrict__ ei,
                                                        int* __restrict__ cnt,
                                                        unsigned int* __restrict__ packed_out) {
    __shared__ int hcnt[NBUCKET];
    __shared__ int excl[NBUCKET];
    __shared__ int lcur[NBUCKET];
    __shared__ int gbase[NBUCKET];
    __shared__ int wsum[8];
    __shared__ unsigned int staged[PTILE];
    __shared__ unsigned short sbkt[PTILE];

    const int t = threadIdx.x;

    if (blockIdx.x < GEMM_BLOCKS) {
        // ---------------- GEMM path: 8 waves, each owns a 16x64 tile --------
        const int wv = t >> 6, lane = t & 63;
        const int q = lane >> 4, m = lane & 15;
        const int row0 = blockIdx.x * 128 + wv * 16;
        const int arow = row0 + m;
        const int arl = arow < N_NODES ? arow : N_NODES - 1;
        const float* xr = x + (size_t)arl * IN_CH + q * 8;
        const short8* wf = (const short8*)wfrag;

        f32x4 acc0 = {0.f,0.f,0.f,0.f}, acc1 = acc0, acc2 = acc0, acc3 = acc0;

        #pragma unroll
        for (int ks = 0; ks < 8; ++ks) {
            const float4 a0 = *(const float4*)(xr + ks * 32);
            const float4 a1 = *(const float4*)(xr + ks * 32 + 4);
            short8 af;
            af[0] = (short)f2bf(a0.x); af[1] = (short)f2bf(a0.y);
            af[2] = (short)f2bf(a0.z); af[3] = (short)f2bf(a0.w);
            af[4] = (short)f2bf(a1.x); af[5] = (short)f2bf(a1.y);
            af[6] = (short)f2bf(a1.z); af[7] = (short)f2bf(a1.w);
            const short8 b0 = wf[(ks * 4 + 0) * 64 + lane];
            const short8 b1 = wf[(ks * 4 + 1) * 64 + lane];
            const short8 b2 = wf[(ks * 4 + 2) * 64 + lane];
            const short8 b3 = wf[(ks * 4 + 3) * 64 + lane];
            acc0 = __builtin_amdgcn_mfma_f32_16x16x32_bf16(af, b0, acc0, 0, 0, 0);
            acc1 = __builtin_amdgcn_mfma_f32_16x16x32_bf16(af, b1, acc1, 0, 0, 0);
            acc2 = __builtin_amdgcn_mfma_f32_16x16x32_bf16(af, b2, acc2, 0, 0, 0);
            acc3 = __builtin_amdgcn_mfma_f32_16x16x32_bf16(af, b3, acc3, 0, 0, 0);
        }

        #pragma unroll
        for (int r = 0; r < 4; ++r) {
            const int row = row0 + q * 4 + r;
            if (row < N_NODES) {
                unsigned short* o = xwb + (size_t)row * HID_CH + m;
                o[0]  = f2bf(acc0[r]);
                o[16] = f2bf(acc1[r]);
                o[32] = f2bf(acc2[r]);
                o[48] = f2bf(acc3[r]);
            }
        }
        return;
    }

    // ---------------- partition path: tile of 4096 edges --------------------
    const int tile0 = (blockIdx.x - GEMM_BLOCKS) * PTILE;
    const int tcnt = min(PTILE, N_EDGES - tile0);

    for (int i = t; i < NBUCKET; i += 512) hcnt[i] = 0;
    __syncthreads();

    // int4 edge loads: 2 rounds x 512 threads x 4 edges. N_EDGES % 4 == 0, so
    // each int4 is fully in- or out-of-bounds. Order within tile is irrelevant.
    int es[8], ed[8];
    #pragma unroll
    for (int r = 0; r < 2; ++r) {
        const int base = tile0 + (r * 512 + t) * 4;
        if (base < N_EDGES) {
            const int4 s4 = *(const int4*)(ei + base);
            const int4 d4 = *(const int4*)(ei + N_EDGES + base);
            es[r*4+0] = s4.x; es[r*4+1] = s4.y; es[r*4+2] = s4.z; es[r*4+3] = s4.w;
            ed[r*4+0] = d4.x; ed[r*4+1] = d4.y; ed[r*4+2] = d4.z; ed[r*4+3] = d4.w;
        } else {
            #pragma unroll
            for (int j = 0; j < 4; ++j) es[r*4+j] = -1;
        }
    }
    #pragma unroll
    for (int i = 0; i < 8; ++i)
        if (es[i] >= 0) atomicAdd(&hcnt[ed[i] >> 6], 1);
    __syncthreads();

    // exclusive scan of 782 counts: pair-per-thread + shfl wave-scan
    const int b0 = 2 * t, b1 = 2 * t + 1;
    const int c0 = (b0 < NBUCKET) ? hcnt[b0] : 0;
    const int c1 = (b1 < NBUCKET) ? hcnt[b1] : 0;
    const int v = c0 + c1;
    int s = v;
    #pragma unroll
    for (int off = 1; off < 64; off <<= 1) {
        const int u = __shfl_up(s, off, 64);
        if ((t & 63) >= off) s += u;
    }
    if ((t & 63) == 63) wsum[t >> 6] = s;
    __syncthreads();
    if (t < 8) {
        const int ws = wsum[t];
        int si = ws;
        #pragma unroll
        for (int off = 1; off < 8; off <<= 1) {
            const int u = __shfl_up(si, off, 64);
            if (t >= off) si += u;
        }
        wsum[t] = si - ws;   // exclusive base for wave t
    }
    __syncthreads();
    const int ex = s - v + wsum[t >> 6];
    if (b0 < NBUCKET) {
        excl[b0] = ex; lcur[b0] = ex;
        if (c0 > 0) gbase[b0] = b0 * CAPB + atomicAdd(&cnt[b0], c0);
    }
    if (b1 < NBUCKET) {
        excl[b1] = ex + c0; lcur[b1] = ex + c0;
        if (c1 > 0) gbase[b1] = b1 * CAPB + atomicAdd(&cnt[b1], c1);
    }
    __syncthreads();

    #pragma unroll
    for (int i = 0; i < 8; ++i) {
        if (es[i] >= 0) {
            const int b = ed[i] >> 6;
            const int pos = atomicAdd(&lcur[b], 1);
            staged[pos] = ((unsigned int)(ed[i] & 63) << 16) | (unsigned int)es[i];
            sbkt[pos] = (unsigned short)b;
        }
    }
    __syncthreads();

    #pragma unroll
    for (int i = 0; i < 8; ++i) {
        const int idx = t + i * 512;
        if (idx < tcnt) {
            const int b = sbkt[idx];
            packed_out[gbase[b] + (idx - excl[b])] = staged[idx];
        }
    }
}

// ---------------------------------------------------------------------------
// Kernel 2: per-bucket aggregate (64 nodes) — R9-proven shape. In-LDS
// counting sort (wave-0 shfl scan; packed read twice from L2 instead of LDS
// staging), then slot-gather: wave w owns nodes {w*8..w*8+7} exclusively ->
// plain LDS read-add-write. ushort4 gathers (512 B / wave instr), 4-deep ILP.
// Fused bias + PReLU.
// ---------------------------------------------------------------------------
__global__ __launch_bounds__(512) void aggregate_kernel(const unsigned short* __restrict__ xwb,
                                                        const unsigned int* __restrict__ packed,
                                                        const int* __restrict__ cnt,
                                                        const float* __restrict__ bias,
                                                        const float* __restrict__ prelu_a,
                                                        float* __restrict__ out) {
    __shared__ unsigned short ssrc[CAP];      //  4 KB
    __shared__ int hcnt[AG_ROWS];
    __shared__ int hexcl[AG_ROWS];
    __shared__ int hcur[AG_ROWS];
    __shared__ float acc[AG_ROWS * HID_CH];   // 16 KB

    const int b = blockIdx.x;
    const int t = threadIdx.x;
    const int beg = b * CAPB;
    const int total = min(cnt[b], CAP);
    const int wv = t >> 6, lane = t & 63;
    const int slot = lane >> 4, c0 = (lane & 15) * 4;

    #pragma unroll
    for (int i = 0; i < 8; ++i) acc[t + i * 512] = 0.f;
    if (t < AG_ROWS) hcnt[t] = 0;
    __syncthreads();

    // histogram pass (packed is L2-resident)
    for (int i = t; i < total; i += 512)
        atomicAdd(&hcnt[packed[beg + i] >> 16], 1);
    __syncthreads();

    // exclusive scan of 64 counts by wave 0 (shfl)
    if (t < AG_ROWS) {
        const int v = hcnt[t];
        int s = v;
        #pragma unroll
        for (int off = 1; off < 64; off <<= 1) {
            const int u = __shfl_up(s, off, 64);
            if (t >= off) s += u;
        }
        hexcl[t] = s - v;
        hcur[t]  = s - v;
    }
    __syncthreads();

    // reorder pass: packed re-read, scatter src ids into node-sorted runs
    for (int i = t; i < total; i += 512) {
        const unsigned int p = packed[beg + i];
        const int pos = atomicAdd(&hcur[p >> 16], 1);
        ssrc[pos] = (unsigned short)(p & 0xFFFFu);
    }
    __syncthreads();

    // slot-gather: wave wv owns nodes wv*8 .. wv*8+7; 4 loads in flight
    #pragma unroll
    for (int k = 0; k < 8; ++k) {
        const int nl = wv * 8 + k;
        const int rb = hexcl[nl];
        const int re = rb + hcnt[nl];
        float4 a4 = make_float4(0.f, 0.f, 0.f, 0.f);
        int i = rb + slot;
        for (; i + 12 < re; i += 16) {
            const int s0 = ssrc[i];
            const int s1 = ssrc[i + 4];
            const int s2 = ssrc[i + 8];
            const int s3 = ssrc[i + 12];
            const ushort4 v0 = *(const ushort4*)(xwb + (size_t)s0 * HID_CH + c0);
            const ushort4 v1 = *(const ushort4*)(xwb + (size_t)s1 * HID_CH + c0);
            const ushort4 v2 = *(const ushort4*)(xwb + (size_t)s2 * HID_CH + c0);
            const ushort4 v3 = *(const ushort4*)(xwb + (size_t)s3 * HID_CH + c0);
            a4.x += bf2f(v0.x) + bf2f(v1.x) + bf2f(v2.x) + bf2f(v3.x);
            a4.y += bf2f(v0.y) + bf2f(v1.y) + bf2f(v2.y) + bf2f(v3.y);
            a4.z += bf2f(v0.z) + bf2f(v1.z) + bf2f(v2.z) + bf2f(v3.z);
            a4.w += bf2f(v0.w) + bf2f(v1.w) + bf2f(v2.w) + bf2f(v3.w);
        }
        for (; i < re; i += 4) {
            const int s = ssrc[i];
            const ushort4 v = *(const ushort4*)(xwb + (size_t)s * HID_CH + c0);
            a4.x += bf2f(v.x); a4.y += bf2f(v.y);
            a4.z += bf2f(v.z); a4.w += bf2f(v.w);
        }
        a4.x += __shfl_xor(a4.x, 16, 64); a4.y += __shfl_xor(a4.y, 16, 64);
        a4.z += __shfl_xor(a4.z, 16, 64); a4.w += __shfl_xor(a4.w, 16, 64);
        a4.x += __shfl_xor(a4.x, 32, 64); a4.y += __shfl_xor(a4.y, 32, 64);
        a4.z += __shfl_xor(a4.z, 32, 64); a4.w += __shfl_xor(a4.w, 32, 64);
        if (slot == 0) {
            float4* ap = (float4*)&acc[nl * HID_CH + c0];
            float4 c4 = *ap;
            c4.x += a4.x; c4.y += a4.y; c4.z += a4.z; c4.w += a4.w;
            *ap = c4;
        }
    }
    __syncthreads();

    // epilogue: bias + PReLU, coalesced float4 writes
    const int node0 = b * AG_ROWS;
    const int nrows = min(AG_ROWS, N_NODES - node0);
    for (int i = t; i < nrows * (HID_CH / 4); i += 512) {
        const int r = i >> 4;
        const int cc = (i & 15) * 4;
        const float4 a4 = *(float4*)&acc[r * HID_CH + cc];
        const float4 bb = *(const float4*)(bias + cc);
        const float4 aa = *(const float4*)(prelu_a + cc);
        float4 rr;
        rr.x = a4.x + bb.x; rr.x = rr.x > 0.f ? rr.x : aa.x * rr.x;
        rr.y = a4.y + bb.y; rr.y = rr.y > 0.f ? rr.y : aa.y * rr.y;
        rr.z = a4.z + bb.z; rr.z = rr.z > 0.f ? rr.z : aa.z * rr.z;
        rr.w = a4.w + bb.w; rr.w = rr.w > 0.f ? rr.w : aa.w * rr.w;
        *(float4*)(out + (size_t)(node0 + r) * HID_CH + cc) = rr;
    }
}

extern "C" void kernel_launch(void* const* d_in, const int* in_sizes, int n_in,
                              void* d_out, int out_size, void* d_ws, size_t ws_size,
                              hipStream_t stream) {
    const float* x       = (const float*)d_in[0];
    const int*   ei      = (const int*)d_in[1];   // [2, E]: src row then dst row
    const float* W       = (const float*)d_in[2];
    const float* bias    = (const float*)d_in[3];
    const float* prelu_a = (const float*)d_in[4];
    float* out = (float*)d_out;

    // workspace layout (16B-aligned)
    char* w = (char*)d_ws;
    unsigned short* xwb    = (unsigned short*)(w);             // 6,400,000 B
    int*            cnt    = (int*)(w + 6400000);              //     3,128 B
    unsigned int*   packed = (unsigned int*)(w + 6403200);     // 4,804,608 B (782*1536*4)
    unsigned short* wfrag  = (unsigned short*)(w + 11207808);  //    32,768 B

    // 0) W -> bf16 B-fragments; zero bucket counters
    wfrag_kernel<<<8, 256, 0, stream>>>(W, wfrag, cnt);

    // 1) fused: gemm (blocks 0..390) + edge partition (blocks 391..586)
    gemm_part_kernel<<<GEMM_BLOCKS + NPT, 512, 0, stream>>>(x, wfrag, xwb, ei, cnt, packed);

    // 2) per-bucket sort + aggregate + bias + PReLU
    aggregate_kernel<<<NBUCKET, 512, 0, stream>>>(xwb, packed, cnt, bias, prelu_a, out);
}